// Round 9
// baseline (270.915 us; speedup 1.0000x reference)
//
#include <hip/hip_runtime.h>
#include <math.h>

#define N 4096
#define D 128
#define H 512
#define KSPLIT 4
// 5 * log2(e): distances stored in log2 domain so all softmax exps are raw v_exp_f32
#define SC_LOG2 7.2134752044f

typedef short bf16x8 __attribute__((ext_vector_type(8)));
typedef float f32x4 __attribute__((ext_vector_type(4)));
typedef unsigned short u16x8 __attribute__((ext_vector_type(8)));
typedef unsigned short u16;
typedef _Float16 f16;
typedef _Float16 f16x4 __attribute__((ext_vector_type(4)));

#define MFMA(a, b, c) __builtin_amdgcn_mfma_f32_16x16x32_bf16((a), (b), (c), 0, 0, 0)

using gvoid = const __attribute__((address_space(1))) void;
using lvoid = __attribute__((address_space(3))) void;

__device__ __forceinline__ float fexp2(float x)
{
#if __has_builtin(__builtin_amdgcn_exp2f)
    return __builtin_amdgcn_exp2f(x);
#else
    return exp2f(x);
#endif
}

// Raw v_sqrt_f32 (~2 ULP) — downstream is f16-quantized anyway.
__device__ __forceinline__ float fsqrt(float x)
{
#if __has_builtin(__builtin_amdgcn_sqrtf)
    return __builtin_amdgcn_sqrtf(x);
#else
    return sqrtf(x);
#endif
}

__device__ __forceinline__ float bf2f(u16 h)
{
    return __uint_as_float(((unsigned)h) << 16);
}

// Round-to-nearest bf16 (unbiased) — for operands whose hi is used ALONE.
__device__ __forceinline__ u16 rtn_bf16(float v)
{
    unsigned u = __float_as_uint(v);
    return (u16)((u + 0x7FFFu + ((u >> 16) & 1u)) >> 16);
}

// RTN split (hi usable alone; lo compensates).
__device__ __forceinline__ void split1(float v, u16& h, u16& l)
{
    u16 hh = rtn_bf16(v);
    float r = v - bf2f(hh);
    h = hh;
    l = rtn_bf16(r);
}

// Cheap truncation split (3 ops); hi+lo pair accuracy identical.
__device__ __forceinline__ void split1_trunc(float v, u16& h, u16& l)
{
    unsigned bv = __float_as_uint(v);
    unsigned hb = bv & 0xFFFF0000u;
    float r = v - __uint_as_float(hb);
    h = (u16)(hb >> 16);
    l = (u16)(__float_as_uint(r) >> 16);
}

// DPP cross-lane move within 16-lane rows (pure VALU — no DS latency).
template <int CTRL>
__device__ __forceinline__ float dppf(float x)
{
    int r = __builtin_amdgcn_update_dpp(0, __float_as_int(x), CTRL, 0xF, 0xF, true);
    return __int_as_float(r);
}

// ---------------------------------------------------------------------------
// RTN-bf16 converter for 4 flat fp32 arrays (hi only).
// ---------------------------------------------------------------------------
struct SplitDesc { const float* src; u16* h; int n; };
struct SplitArgs { SplitDesc d[4]; };

__global__ __launch_bounds__(256) void split_multi(SplitArgs args)
{
    SplitDesc de = args.d[blockIdx.y];
    int idx = (blockIdx.x * 256 + threadIdx.x) * 4;
    if (idx >= de.n) return;
    float4 v = *(const float4*)(de.src + idx);
    ushort4 hv;
    hv.x = rtn_bf16(v.x); hv.y = rtn_bf16(v.y);
    hv.z = rtn_bf16(v.z); hv.w = rtn_bf16(v.w);
    *(ushort4*)(de.h + idx) = hv;
}

// ---------------------------------------------------------------------------
// Cooperative W k-slab staging via global_load_lds (async, scheduler-proof —
// R5-R8's register-prefetch rings were all collapsed by the pre-RA scheduler
// into serialized load-wait-use chains; an LDS-side-effect instruction
// cannot be). Slab = [ROWS out-cols] x [32 k] u16, stored [q][c] (q = 16B
// quarter of the k-range, c = out-col): the B-fragment ds_read_b128 then
// has lanes at stride 16B -> 2-way bank aliasing (free) instead of 8-way.
// LDS dest is linear in slot order (wave-uniform base + lane*16 — m104);
// the per-lane GLOBAL address carries the layout permutation.
// ---------------------------------------------------------------------------
template <int ROWS>
__device__ __forceinline__ void stage_w(const u16* __restrict__ W, int K, int kt,
                                        u16* ws, int t)
{
    constexpr int ISS = ROWS / 128;          // 16B-chunks per thread (512 thr)
    #pragma unroll
    for (int p = 0; p < ISS; ++p) {
        const int slot = t + p * 512;        // 0 .. ROWS*4-1
        const int c = slot & (ROWS - 1);     // out-col
        const int q = slot / ROWS;           // k-quarter (0..3)
        const u16* g = W + (size_t)c * K + kt * 32 + q * 8;
        __builtin_amdgcn_global_load_lds((gvoid*)g,
                                         (lvoid*)(ws + (size_t)slot * 8),
                                         16, 0, 0);
    }
}

// ---------------------------------------------------------------------------
// One generator layer (output width 512 -> x LDS update), T3 2-phase:
// stage(next k-slab) issued BEFORE this step's ds_read+MFMA; single
// __syncthreads per k-step (its vmcnt(0) drain is covered by ~310cy of
// MFMA per SIMD). Buffers WS0/WS1 statically alternated (kt unrolled).
// ---------------------------------------------------------------------------
template <int K, bool RR>
__device__ __forceinline__ void gen_layer(
    u16 (&XhS)[16][520], u16 (&XlS)[16][520],
    u16* WS0, u16* WS1,
    const u16* __restrict__ W, const float* __restrict__ bias,
    int w, int quad, int l16, int t)
{
    const int nb = w * 64;
    constexpr int NT = K >> 5;
    f32x4 acc[4] = {};
    float bl4[4];
    #pragma unroll
    for (int ni = 0; ni < 4; ++ni) bl4[ni] = bias[nb + ni * 16 + l16];
    #pragma unroll
    for (int kt = 0; kt < NT; ++kt) {
        u16* cur = (kt & 1) ? WS1 : WS0;
        u16* nxt = (kt & 1) ? WS0 : WS1;
        if (kt + 1 < NT) stage_w<512>(W, K, kt + 1, nxt, t);
        const int kk = kt * 32 + quad * 8;
        bf16x8 af  = *(const bf16x8*)&XhS[l16][kk];
        bf16x8 alf = *(const bf16x8*)&XlS[l16][kk];
        #pragma unroll
        for (int ni = 0; ni < 4; ++ni) {
            bf16x8 bh = *(const bf16x8*)
                (cur + (size_t)(quad * 512 + nb + ni * 16 + l16) * 8);
            acc[ni] = MFMA(af,  bh, acc[ni]);
            acc[ni] = MFMA(alf, bh, acc[ni]);
        }
        __syncthreads();   // drains this step's stage; nxt ready for kt+1
    }
    // epilogue: cols are wave-private -> no cross-wave hazard on x update
    #pragma unroll
    for (int ni = 0; ni < 4; ++ni) {
        const int col = nb + ni * 16 + l16;
        #pragma unroll
        for (int r = 0; r < 4; ++r) {
            const int row = quad * 4 + r;
            float v = acc[ni][r] + bl4[ni];
            if (RR) {
                float prev = bf2f(XhS[row][col]) + bf2f(XlS[row][col]);
                v = prev + fmaxf(v, 0.0f);
            }
            u16 hh, ll;
            split1_trunc(v, hh, ll);
            XhS[row][col] = hh;
            XlS[row][col] = ll;
        }
    }
    __syncthreads();       // x updated for next layer
}

// ---------------------------------------------------------------------------
// FUSED generator: each block owns 16 rows of x, runs ALL 6 layers with x
// resident in LDS (hi/lo bf16, 33 KB). W streamed via cooperative
// double-buffered global_load_lds (2 x 32 KB). 8 waves x 64-col chunks.
// LDS total 98.8 KB -> 1 block/CU, 2 waves/SIMD.
// ---------------------------------------------------------------------------
__global__ __launch_bounds__(512) void gen_fused(
    const float* __restrict__ eps,
    const u16* __restrict__ Win, const u16* __restrict__ Wblk,
    const u16* __restrict__ Wout,
    const float* __restrict__ b_in, const float* __restrict__ b_blk,
    const float* __restrict__ b_out,
    float* __restrict__ xo, u16* __restrict__ xh)
{
    __shared__ u16 XhS[16][520], XlS[16][520];
    __shared__ u16 WS0[2048 * 8], WS1[2048 * 8];   // 32 KB each
    const int t = threadIdx.x;
    const int w = t >> 6, lane = t & 63;
    const int quad = lane >> 4, l16 = lane & 15;
    const int bm = blockIdx.x * 16;

    // issue layer-0's first W slab FIRST (hides its cold L2/L3 latency
    // under the eps split below), then stage eps rows -> x LDS (split1 RTN)
    stage_w<512>(Win, D, 0, WS0, t);
    {
        int idx = t * 4;                       // 0..2047 over 16x128
        int row = idx >> 7, col = idx & 127;
        float4 v = *(const float4*)(eps + (size_t)(bm + row) * D + col);
        ushort4 hv, lv;
        split1(v.x, hv.x, lv.x); split1(v.y, hv.y, lv.y);
        split1(v.z, hv.z, lv.z); split1(v.w, hv.w, lv.w);
        *(ushort4*)&XhS[row][col] = hv;
        *(ushort4*)&XlS[row][col] = lv;
    }
    __syncthreads();

    gen_layer<D, false>(XhS, XlS, WS0, WS1, Win, b_in, w, quad, l16, t);
    #pragma unroll 1
    for (int i = 0; i < 4; ++i) {
        const u16* Wl = Wblk + (size_t)i * H * H;
        stage_w<512>(Wl, H, 0, WS0, t);
        __syncthreads();
        gen_layer<H, true>(XhS, XlS, WS0, WS1, Wl, b_blk + i * H,
                           w, quad, l16, t);
    }

    // --- last layer: out width 128 (ROWS=128), fp32 xo + RTN xh ---
    {
        const int n0 = w * 16;                 // 8 waves x 16 cols
        constexpr int NT = H >> 5;
        f32x4 acc5 = {};
        const float bl = b_out[n0 + l16];
        stage_w<128>(Wout, H, 0, WS0, t);
        __syncthreads();
        #pragma unroll
        for (int kt = 0; kt < NT; ++kt) {
            u16* cur = (kt & 1) ? WS1 : WS0;
            u16* nxt = (kt & 1) ? WS0 : WS1;
            if (kt + 1 < NT) stage_w<128>(Wout, H, kt + 1, nxt, t);
            const int kk = kt * 32 + quad * 8;
            bf16x8 af  = *(const bf16x8*)&XhS[l16][kk];
            bf16x8 alf = *(const bf16x8*)&XlS[l16][kk];
            bf16x8 bh = *(const bf16x8*)
                (cur + (size_t)(quad * 128 + n0 + l16) * 8);
            acc5 = MFMA(af,  bh, acc5);
            acc5 = MFMA(alf, bh, acc5);
            __syncthreads();
        }
        const int col = n0 + l16;
        #pragma unroll
        for (int r = 0; r < 4; ++r) {
            const int gm = bm + quad * 4 + r;
            float v = acc5[r] + bl;
            xo[(size_t)gm * D + col] = v;
            xh[(size_t)gm * D + col] = rtn_bf16(v);
        }
    }
}

// ---------------------------------------------------------------------------
// Deterministic row-norms: nx from xo, ny from y_pos. 4 threads/row, fixed
// order + fixed 2-step shfl tree (replaces the fp-atomic path that tripped
// the bit-identical-replay check).
// ---------------------------------------------------------------------------
__global__ __launch_bounds__(256) void rownorm(
    const float* __restrict__ X, const float* __restrict__ Y,
    float* __restrict__ nx, float* __restrict__ ny)
{
    const float* src = blockIdx.y ? Y : X;
    float* dst = blockIdx.y ? ny : nx;
    const int t = threadIdx.x;
    const int row = blockIdx.x * 64 + (t >> 2);
    const int q = t & 3;
    const float* rp = src + (size_t)row * D + q * 32;
    float s = 0.f;
    #pragma unroll
    for (int i = 0; i < 8; ++i) {
        float4 v = *(const float4*)(rp + i * 4);
        s += v.x * v.x + v.y * v.y + v.z * v.z + v.w * v.w;
    }
    s += __shfl_xor(s, 1);
    s += __shfl_xor(s, 2);
    if (q == 0) dst[row] = s;
}

// ---------------------------------------------------------------------------
// Transpose + RTN-bf16 (pure — norms moved to rownorm).
// ---------------------------------------------------------------------------
__global__ __launch_bounds__(256) void transpose_rtn(
    const float* __restrict__ X, const float* __restrict__ Y,
    u16* __restrict__ Xth, u16* __restrict__ Yth)
{
    const float* src = blockIdx.z ? Y : X;
    u16* th = blockIdx.z ? Yth : Xth;
    __shared__ float tile[32][33];
    const int t = threadIdx.x;
    const int r0 = blockIdx.x * 32, c0 = blockIdx.y * 32;
    {
        int rit = t >> 3, coff = (t & 7) * 4;
        float4 v = *(const float4*)(src + (size_t)(r0 + rit) * D + c0 + coff);
        tile[rit][coff + 0] = v.x; tile[rit][coff + 1] = v.y;
        tile[rit][coff + 2] = v.z; tile[rit][coff + 3] = v.w;
    }
    __syncthreads();
    {
        int cit = t >> 3, roff = (t & 7) * 4;
        ushort4 hv;
        hv.x = rtn_bf16(tile[roff + 0][cit]);
        hv.y = rtn_bf16(tile[roff + 1][cit]);
        hv.z = rtn_bf16(tile[roff + 2][cit]);
        hv.w = rtn_bf16(tile[roff + 3][cit]);
        *(ushort4*)(th + (size_t)(c0 + cit) * N + r0 + roff) = hv;
    }
}

// ---------------------------------------------------------------------------
// Distance via SINGLE RTN-bf16 MFMA, fused stats, pos+neg merged. A fp16,
// stored in LOG2 domain. Epilogue in POSITIVE s-domain: raw v_sqrt_f32,
// SC^2 folded into norms, per-element diag cndmask.
// Tile 128(M)x128(N), 4 waves each owning 32 rows x full 128 cols.
// ---------------------------------------------------------------------------
__global__ __launch_bounds__(256) void dist_fused(
    const u16* __restrict__ Xh, const u16* __restrict__ Yh,
    const float* __restrict__ nx, const float* __restrict__ ny,
    f16* __restrict__ Apos, f16* __restrict__ Aneg,
    float* __restrict__ prm_p, float* __restrict__ prs_p,
    float* __restrict__ pcm_p, float* __restrict__ pcs_p,
    float* __restrict__ prm_n, float* __restrict__ prs_n)
{
    const int mat = blockIdx.z;                // 0: X vs Y ; 1: X vs X
    const u16* Bhp = mat ? Xh : Yh;
    const float* nb = mat ? nx : ny;
    f16* Out = mat ? Aneg : Apos;
    float* prm = mat ? prm_n : prm_p;
    float* prs = mat ? prs_n : prs_p;

    __shared__ u16 XhS[128][40], YhS[128][40];
    const int t = threadIdx.x;
    const int w = t >> 6, lane = t & 63;
    const int quad = lane >> 4, l16 = lane & 15;
    const int bm = blockIdx.y * 128, bn = blockIdx.x * 128;
    f32x4 acc[2][8] = {};

    for (int k0 = 0; k0 < D; k0 += 32) {
        __syncthreads();
        #pragma unroll
        for (int p = 0; p < 2; ++p) {
            int slot = t + p * 256;            // 512 slots = 128 rows x 4 octets
            int row = slot >> 2, koff = (slot & 3) << 3;
            *(u16x8*)&XhS[row][koff] =
                *(const u16x8*)(Xh + (size_t)(bm + row) * D + k0 + koff);
        }
        #pragma unroll
        for (int p = 0; p < 2; ++p) {
            int slot = t + p * 256;
            int row = slot >> 2, koff = (slot & 3) << 3;
            int pr = ((row & 3) << 4) | ((row & 63) >> 2) | (row & 64);
            int kf = koff ^ (((pr >> 4) & 3) << 3);
            *(u16x8*)&YhS[pr][kf] =
                *(const u16x8*)(Bhp + (size_t)(bn + row) * D + k0 + koff);
        }
        __syncthreads();
        bf16x8 af[2], bhf[8];
        #pragma unroll
        for (int mi = 0; mi < 2; ++mi)
            af[mi] = *(const bf16x8*)&XhS[w * 32 + mi * 16 + l16][quad * 8];
        #pragma unroll
        for (int ni = 0; ni < 8; ++ni) {
            int nn = ni & 3, hf = ni >> 2;
            bhf[ni] = *(const bf16x8*)
                &YhS[hf * 64 + nn * 16 + l16][(quad * 8) ^ (nn << 3)];
        }
        #pragma unroll
        for (int mi = 0; mi < 2; ++mi)
            #pragma unroll
            for (int ni = 0; ni < 8; ++ni)
                acc[mi][ni] = MFMA(af[mi], bhf[ni], acc[mi][ni]);
    }
    // lane's 8 j's: jb..jb+3 and jb+64..jb+67
    const int jb = bn + (l16 << 2);
    const float SC2 = SC_LOG2 * SC_LOG2;
    const float c2 = -2.0f * SC2;
    const float4 n0v = *(const float4*)(nb + jb);
    const float4 n1v = *(const float4*)(nb + jb + 64);
    const float nl[8] = {n0v.x * SC2, n0v.y * SC2, n0v.z * SC2, n0v.w * SC2,
                         n1v.x * SC2, n1v.y * SC2, n1v.z * SC2, n1v.w * SC2};
    // --- transform in place to s = dist*SC (positive domain) + f16 stores ---
    #pragma unroll
    for (int mi = 0; mi < 2; ++mi)
        #pragma unroll
        for (int r = 0; r < 4; ++r) {
            const int gm = bm + w * 32 + mi * 16 + quad * 4 + r;
            const float nxm = nx[gm] * SC2;
            f16x4 ov0, ov1;
            #pragma unroll
            for (int nn = 0; nn < 4; ++nn) {
                float s0 = fsqrt(fmaxf(
                    fmaf(acc[mi][nn][r], c2, nxm + nl[nn]), 0.f));
                float s1 = fsqrt(fmaxf(
                    fmaf(acc[mi][4 + nn][r], c2, nxm + nl[4 + nn]), 0.f));
                if (mat) {
                    if (gm == jb + nn) s0 = 5.0e6f;
                    if (gm == jb + 64 + nn) s1 = 5.0e6f;
                }
                acc[mi][nn][r] = s0;
                acc[mi][4 + nn][r] = s1;
                ov0[nn] = (f16)(-s0);
                ov1[nn] = (f16)(-s1);
            }
            *(f16x4*)(Out + (size_t)gm * N + jb) = ov0;
            *(f16x4*)(Out + (size_t)gm * N + jb + 64) = ov1;
        }
    // --- row mins of s (== -row max of a): in-lane over 8 ni, DPP over l16 ---
    float m[2][4];
    #pragma unroll
    for (int mi = 0; mi < 2; ++mi)
        #pragma unroll
        for (int r = 0; r < 4; ++r) {
            float v = fminf(fminf(fminf(acc[mi][0][r], acc[mi][1][r]),
                                  fminf(acc[mi][2][r], acc[mi][3][r])),
                            fminf(fminf(acc[mi][4][r], acc[mi][5][r]),
                                  fminf(acc[mi][6][r], acc[mi][7][r])));
            v = fminf(v, dppf<0xB1>(v));
            v = fminf(v, dppf<0x4E>(v));
            v = fminf(v, dppf<0x141>(v));
            v = fminf(v, dppf<0x140>(v));
            m[mi][r] = v;
        }
    // --- wave-shared shift mn (min s over the wave's 32 rows x 128 cols) ---
    float mn = fminf(fminf(fminf(m[0][0], m[0][1]), fminf(m[0][2], m[0][3])),
                     fminf(fminf(m[1][0], m[1][1]), fminf(m[1][2], m[1][3])));
    mn = fminf(mn, __shfl_xor(mn, 16));
    mn = fminf(mn, __shfl_xor(mn, 32));
    // --- single exp pass: e = 2^(mn - s) feeds row sums (sig) + col sums ---
    float sig[2][4] = {};
    float cs[8] = {};
    #pragma unroll
    for (int mi = 0; mi < 2; ++mi)
        #pragma unroll
        for (int ni = 0; ni < 8; ++ni) {
            float e0 = fexp2(mn - acc[mi][ni][0]);
            float e1 = fexp2(mn - acc[mi][ni][1]);
            float e2 = fexp2(mn - acc[mi][ni][2]);
            float e3 = fexp2(mn - acc[mi][ni][3]);
            sig[mi][0] += e0; sig[mi][1] += e1;
            sig[mi][2] += e2; sig[mi][3] += e3;
            cs[ni] += (e0 + e1) + (e2 + e3);
        }
    // --- row partials: DPP tree-sum sig, rescale to row max (a-domain) ---
    const int ct = blockIdx.x;
    #pragma unroll
    for (int mi = 0; mi < 2; ++mi)
        #pragma unroll
        for (int r = 0; r < 4; ++r) {
            float s = sig[mi][r];
            s += dppf<0xB1>(s);
            s += dppf<0x4E>(s);
            s += dppf<0x141>(s);
            s += dppf<0x140>(s);
            s *= fexp2(m[mi][r] - mn);
            if (l16 == 0) {
                int grow = bm + w * 32 + mi * 16 + quad * 4 + r;
                prm[(size_t)ct * N + grow] = -m[mi][r];
                prs[(size_t)ct * N + grow] = s;
            }
        }
    // --- col partials (pos only): quad-reduce cs, shift is -mn (uniform) ---
    if (mat == 0) {
        const int rt = blockIdx.y * 4 + w;      // 32-row tiles -> 128 planes
        #pragma unroll
        for (int ni = 0; ni < 8; ++ni) {
            cs[ni] += __shfl_xor(cs[ni], 16);
            cs[ni] += __shfl_xor(cs[ni], 32);
        }
        if (quad == 0) {
            float4 c0 = {cs[0], cs[1], cs[2], cs[3]};
            float4 c1 = {cs[4], cs[5], cs[6], cs[7]};
            float4 m4 = {-mn, -mn, -mn, -mn};
            *(float4*)(pcs_p + (size_t)rt * N + jb) = c0;
            *(float4*)(pcs_p + (size_t)rt * N + jb + 64) = c1;
            *(float4*)(pcm_p + (size_t)rt * N + jb) = m4;
            *(float4*)(pcm_p + (size_t)rt * N + jb + 64) = m4;
        }
    }
}

// ---------------------------------------------------------------------------
// Combine partials into row/col softmax stats — parallel (192 x 256).
// ---------------------------------------------------------------------------
__global__ __launch_bounds__(256) void stats_combine(
    const float* __restrict__ prm_p, const float* __restrict__ prs_p,
    const float* __restrict__ prm_n, const float* __restrict__ prs_n,
    const float* __restrict__ pcm_p, const float* __restrict__ pcs_p,
    float* __restrict__ m_row, float* __restrict__ isr,
    float* __restrict__ m_col, float* __restrict__ isc)
{
    __shared__ float Ms[4][64], Ss[4][64];
    const int t = threadIdx.x;
    const int g = t >> 6, l = t & 63;
    const int idx = blockIdx.x * 64 + l;

    float m = -3.0e38f, s = 0.f;
    if (idx < N) {
        const int i = idx;
        const int c0 = g * 8;
        #pragma unroll 4
        for (int c = c0; c < c0 + 8; ++c) {
            m = fmaxf(m, prm_p[(size_t)c * N + i]);
            m = fmaxf(m, prm_n[(size_t)c * N + i]);
        }
        #pragma unroll 4
        for (int c = c0; c < c0 + 8; ++c) {
            s += prs_p[(size_t)c * N + i] * fexp2(prm_p[(size_t)c * N + i] - m);
            s += prs_n[(size_t)c * N + i] * fexp2(prm_n[(size_t)c * N + i] - m);
        }
    } else {
        const int mat = (idx - N) >> 12;
        const int j = idx & (N - 1);
        const float* pm = mat ? prm_n : pcm_p;
        const float* ps = mat ? prs_n : pcs_p;
        const int cnt = mat ? 8 : 32;
        const int cb = g * cnt;
        #pragma unroll 4
        for (int c = cb; c < cb + cnt; ++c)
            m = fmaxf(m, pm[(size_t)c * N + j]);
        #pragma unroll 4
        for (int c = cb; c < cb + cnt; ++c)
            s += ps[(size_t)c * N + j] * fexp2(pm[(size_t)c * N + j] - m);
    }
    Ms[g][l] = m; Ss[g][l] = s;
    __syncthreads();
    if (g == 0) {
        float m0 = Ms[0][l], m1 = Ms[1][l], m2 = Ms[2][l], m3 = Ms[3][l];
        float mm = fmaxf(fmaxf(m0, m1), fmaxf(m2, m3));
        float ss = Ss[0][l] * fexp2(m0 - mm) + Ss[1][l] * fexp2(m1 - mm)
                 + Ss[2][l] * fexp2(m2 - mm) + Ss[3][l] * fexp2(m3 - mm);
        if (idx < N) {
            m_row[idx] = mm;
            isr[idx] = 1.0f / sqrtf(ss);
        } else {
            const int mat = (idx - N) >> 12;
            const int j = idx & (N - 1);
            m_col[mat * N + j] = mm;
            isc[mat * N + j] = 1.0f / sqrtf(ss);
        }
    }
}

// ---------------------------------------------------------------------------
// pv via MFMA: A fp16 tile (log2 domain) -> P (fp32 rowsums -> per-KSPLIT
// partial stores, deterministic), split P (trunc) to bf16 hi/lo in LDS,
// MFMA P @ B (B = RTN-bf16 transposed [d][j], hi only).
// ---------------------------------------------------------------------------
__global__ __launch_bounds__(256) void pv_mfma(
    const f16* __restrict__ Apos, const f16* __restrict__ Aneg,
    const u16* __restrict__ Yth, const u16* __restrict__ Xth,
    const float* __restrict__ m_row, const float* __restrict__ isr,
    const float* __restrict__ m_col, const float* __restrict__ isc,
    float* __restrict__ u_part, float* __restrict__ w_part,
    float* __restrict__ sp_part, float* __restrict__ sn_part)
{
    const int mat = blockIdx.z;
    const f16* Am = mat ? Aneg : Apos;
    const u16* Bh = mat ? Xth : Yth;
    const float* mc = m_col + mat * N;
    const float* ic = isc + mat * N;
    float* Cp = (mat ? w_part : u_part) + (size_t)blockIdx.y * (N * D);
    float* spn = (mat ? sn_part : sp_part) + (size_t)blockIdx.y * N;

    __shared__ u16 BhS[128][72];
    __shared__ u16 PhS[64][72], PlS[64][72];
    __shared__ float mrS[64], isrS[64];

    const int t = threadIdx.x;
    const int w = t >> 6, lane = t & 63;
    const int quad = lane >> 4, l16 = lane & 15;
    const int bm = blockIdx.x * 64;
    const int jbase = blockIdx.y * (N / KSPLIT);
    const int arow = t >> 4;          // 0..15
    const int aj = (t & 15) << 2;     // 0..60

    if (t < 64) { mrS[t] = m_row[bm + t]; isrS[t] = isr[bm + t]; }

    f32x4 acc[8] = {};
    float rs[4] = {0.f, 0.f, 0.f, 0.f};

    for (int jt = 0; jt < (N / KSPLIT) / 64; ++jt) {
        const int j0 = jbase + jt * 64;
        __syncthreads();   // protect previous iteration's LDS reads (+ mrS init)
        #pragma unroll
        for (int p = 0; p < 4; ++p) {
            int slot = t + p * 256;
            int d = slot >> 3, joff = (slot & 7) << 3;
            *(u16x8*)&BhS[d][joff] = *(const u16x8*)(Bh + (size_t)d * N + j0 + joff);
        }
        float4 mcv = *(const float4*)(mc + j0 + aj);
        float4 icv = *(const float4*)(ic + j0 + aj);
        #pragma unroll
        for (int s = 0; s < 4; ++s) {
            int row = arow + s * 16;
            f16x4 av = *(const f16x4*)(Am + (size_t)(bm + row) * N + j0 + aj);
            float mr = mrS[row], sr = isrS[row];
            float p0 = fexp2((float)av.x - 0.5f * (mr + mcv.x)) * (sr * icv.x);
            float p1 = fexp2((float)av.y - 0.5f * (mr + mcv.y)) * (sr * icv.y);
            float p2 = fexp2((float)av.z - 0.5f * (mr + mcv.z)) * (sr * icv.z);
            float p3 = fexp2((float)av.w - 0.5f * (mr + mcv.w)) * (sr * icv.w);
            rs[s] += p0 + p1 + p2 + p3;
            ushort4 hv, lv;
            split1_trunc(p0, hv.x, lv.x); split1_trunc(p1, hv.y, lv.y);
            split1_trunc(p2, hv.z, lv.z); split1_trunc(p3, hv.w, lv.w);
            *(ushort4*)&PhS[row][aj] = hv;
            *(ushort4*)&PlS[row][aj] = lv;
        }
        __syncthreads();
        #pragma unroll
        for (int ks = 0; ks < 2; ++ks) {
            const int kk = ks * 32 + quad * 8;
            bf16x8 ph = *(const bf16x8*)&PhS[w * 16 + l16][kk];
            bf16x8 pl = *(const bf16x8*)&PlS[w * 16 + l16][kk];
            #pragma unroll
            for (int ni = 0; ni < 8; ++ni) {
                bf16x8 bh = *(const bf16x8*)&BhS[ni * 16 + l16][kk];
                acc[ni] = MFMA(ph, bh, acc[ni]);
                acc[ni] = MFMA(pl, bh, acc[ni]);
            }
        }
    }
    #pragma unroll
    for (int ni = 0; ni < 8; ++ni)
        #pragma unroll
        for (int r = 0; r < 4; ++r) {
            int row = w * 16 + quad * 4 + r;
            int col = ni * 16 + l16;
            Cp[(size_t)(bm + row) * D + col] = acc[ni][r];
        }
    #pragma unroll
    for (int s = 0; s < 4; ++s) {
        float v = rs[s];
        v += __shfl_xor(v, 1); v += __shfl_xor(v, 2);
        v += __shfl_xor(v, 4); v += __shfl_xor(v, 8);
        if (l16 == 0) spn[bm + arow + s * 16] = v;   // unique writer per (y,row)
    }
}

// ---------------------------------------------------------------------------
// Sum split-K partials (fixed order), V = sn*u - sp*sn*w, per-block V^2
// partial into acc_part (no atomics — finalize does the deterministic sum).
// ---------------------------------------------------------------------------
__global__ __launch_bounds__(256) void final_reduce(const float* __restrict__ u_part,
    const float* __restrict__ w_part, const float* __restrict__ sp_part,
    const float* __restrict__ sn_part, double* __restrict__ acc_part)
{
    __shared__ float red[256];
    const int t = threadIdx.x;
    const int idx = blockIdx.x * 256 + t;
    float u = 0.f, w = 0.f;
    #pragma unroll
    for (int c = 0; c < KSPLIT; ++c) {
        u += u_part[(size_t)c * (N * D) + idx];
        w += w_part[(size_t)c * (N * D) + idx];
    }
    const int i = idx >> 7;
    float sp = 0.f, sn = 0.f;
    #pragma unroll
    for (int c = 0; c < KSPLIT; ++c) {
        sp += sp_part[(size_t)c * N + i];
        sn += sn_part[(size_t)c * N + i];
    }
    const float v = sn * u - sp * sn * w;
    red[t] = v * v; __syncthreads();
    for (int s = 128; s > 0; s >>= 1) { if (t < s) red[t] += red[t + s]; __syncthreads(); }
    if (!t) acc_part[blockIdx.x] = (double)red[0];
}

// ---------------------------------------------------------------------------
// Deterministic final sum: 2048 double partials, fixed-order + fixed tree.
// ---------------------------------------------------------------------------
__global__ __launch_bounds__(256) void finalize(const double* __restrict__ acc_part,
                                                float* __restrict__ out)
{
    __shared__ double red[256];
    const int t = threadIdx.x;
    double s = 0.0;
    #pragma unroll
    for (int i = 0; i < 8; ++i) s += acc_part[t + i * 256];
    red[t] = s; __syncthreads();
    for (int st = 128; st > 0; st >>= 1) {
        if (t < st) red[t] += red[t + st];
        __syncthreads();
    }
    if (!t) out[0] = (float)(red[0] * (1.0 / ((double)N * (double)D)));
}

// ---------------------------------------------------------------------------
extern "C" void kernel_launch(void* const* d_in, const int* in_sizes, int n_in,
                              void* d_out, int out_size, void* d_ws, size_t ws_size,
                              hipStream_t stream)
{
    const float* y_pos = (const float*)d_in[0];
    const float* eps   = (const float*)d_in[1];
    const float* W_in  = (const float*)d_in[2];
    const float* b_in  = (const float*)d_in[3];
    const float* W_blk = (const float*)d_in[4];
    const float* b_blk = (const float*)d_in[5];
    const float* W_out = (const float*)d_in[6];
    const float* b_out = (const float*)d_in[7];
    float* out = (float*)d_out;
    (void)in_sizes; (void)n_in; (void)out_size; (void)ws_size;

    char* p = (char*)d_ws;
    auto alloc = [&](size_t bytes) {
        char* r = p;
        p += (bytes + 255) & ~(size_t)255;
        return r;
    };
    // --- small arrays ---
    double* acc_part = (double*)alloc(2048 * 8);
    float* sp_part = (float*)alloc((size_t)KSPLIT * N * 4);
    float* sn_part = (float*)alloc((size_t)KSPLIT * N * 4);
    float* m_row  = (float*)alloc(N * 4);
    float* isr    = (float*)alloc(N * 4);
    float* m_col  = (float*)alloc(2 * N * 4);
    float* isc    = (float*)alloc(2 * N * 4);
    float* nx     = (float*)alloc(N * 4);
    float* ny     = (float*)alloc(N * 4);
    // --- xo fp32 + bf16 x/y arrays (hi only) ---
    float* xo  = (float*)alloc((size_t)N * D * 4);
    u16* xh    = (u16*)alloc((size_t)N * D * 2);
    u16* xth   = (u16*)alloc((size_t)N * D * 2);
    u16* yh    = (u16*)alloc((size_t)N * D * 2);
    u16* yth   = (u16*)alloc((size_t)N * D * 2);
    // --- shared region (16 MB): weights hi (2.3 MB, dead after gen_fused),
    //     then stats partials (6 MB), then u/w_part (16 MB) ---
    char* genreg = alloc((size_t)KSPLIT * N * D * 4 * 2);
    u16* wih = (u16*)genreg;
    u16* wbh = wih + (size_t)H * D;
    u16* woh = wbh + (size_t)4 * H * H;
    // aliases (disjoint lifetimes, stream-ordered):
    float* prm_p = (float*)genreg;                 // 32*N each = 0.5 MB
    float* prs_p = prm_p + 32 * N;
    float* prm_n = prs_p + 32 * N;
    float* prs_n = prm_n + 32 * N;
    float* pcm_p = prs_n + 32 * N;                 // 128*N = 2 MB each
    float* pcs_p = pcm_p + 128 * N;                // ends at 6 MB
    float* u_part = (float*)genreg;                // KSPLIT*N*D = 8 MB
    float* w_part = u_part + (size_t)KSPLIT * N * D;
    // --- the big ones (64 MB, fp16) ---
    f16* Apos = (f16*)alloc((size_t)N * N * 2);
    f16* Aneg = (f16*)alloc((size_t)N * N * 2);

    // --- RTN-convert y_pos + weights to bf16 hi ---
    SplitArgs sa;
    sa.d[0] = { y_pos, yh,  N * D };
    sa.d[1] = { W_in,  wih, H * D };
    sa.d[2] = { W_blk, wbh, 4 * H * H };
    sa.d[3] = { W_out, woh, D * H };
    split_multi<<<dim3(1024, 4), 256, 0, stream>>>(sa);

    // --- FUSED generator: whole 6-layer chain, x LDS-resident ---
    gen_fused<<<N / 16, 512, 0, stream>>>(eps, wih, wbh, woh,
                                          b_in, b_blk, b_out, xo, xh);

    // --- deterministic row norms (nx from xo, ny from y_pos) ---
    rownorm<<<dim3(N / 64, 2), 256, 0, stream>>>(xo, y_pos, nx, ny);

    // --- RTN transposes ---
    transpose_rtn<<<dim3(N / 32, D / 32, 2), 256, 0, stream>>>(
        xo, y_pos, xth, yth);

    // --- distance matrices (fp16 log2-domain, single-bf16 MFMA) + stats ---
    dist_fused<<<dim3(N / 128, N / 128, 2), 256, 0, stream>>>(
        xh, yh, nx, ny, Apos, Aneg,
        prm_p, prs_p, pcm_p, pcs_p, prm_n, prs_n);

    // --- combine partials into m_row/isr, m_col/isc (parallel) ---
    stats_combine<<<192, 256, 0, stream>>>(prm_p, prs_p, prm_n, prs_n,
                                           pcm_p, pcs_p,
                                           m_row, isr, m_col, isc);

    // --- P@V via MFMA (P built on the fly; sp/sn deterministic partials) ---
    pv_mfma<<<dim3(N / 64, KSPLIT, 2), 256, 0, stream>>>(Apos, Aneg,
        yth, xth, m_row, isr, m_col, isc, u_part, w_part, sp_part, sn_part);

    // --- combine partials, V^2 reduction (no atomics) ---
    final_reduce<<<(N * D) / 256, 256, 0, stream>>>(u_part, w_part,
                                                    sp_part, sn_part, acc_part);
    finalize<<<1, 256, 0, stream>>>(acc_part, out);
}

// Round 10
// 190.434 us; speedup vs baseline: 1.4226x; 1.4226x over previous
//
#include <hip/hip_runtime.h>
#include <math.h>

#define N 4096
#define D 128
#define H 512
#define KSPLIT 4
// 5 * log2(e): distances stored in log2 domain so all softmax exps are raw v_exp_f32
#define SC_LOG2 7.2134752044f

typedef short bf16x8 __attribute__((ext_vector_type(8)));
typedef float f32x4 __attribute__((ext_vector_type(4)));
typedef unsigned short u16x8 __attribute__((ext_vector_type(8)));
typedef unsigned short u16;
typedef _Float16 f16;
typedef _Float16 f16x4 __attribute__((ext_vector_type(4)));

#define MFMA(a, b, c) __builtin_amdgcn_mfma_f32_16x16x32_bf16((a), (b), (c), 0, 0, 0)

__device__ __forceinline__ float fexp2(float x)
{
#if __has_builtin(__builtin_amdgcn_exp2f)
    return __builtin_amdgcn_exp2f(x);
#else
    return exp2f(x);
#endif
}

// Raw v_sqrt_f32 (~2 ULP) — downstream is f16-quantized anyway.
__device__ __forceinline__ float fsqrt(float x)
{
#if __has_builtin(__builtin_amdgcn_sqrtf)
    return __builtin_amdgcn_sqrtf(x);
#else
    return sqrtf(x);
#endif
}

__device__ __forceinline__ float bf2f(u16 h)
{
    return __uint_as_float(((unsigned)h) << 16);
}

// Round-to-nearest bf16 (unbiased) — for operands whose hi is used ALONE.
__device__ __forceinline__ u16 rtn_bf16(float v)
{
    unsigned u = __float_as_uint(v);
    return (u16)((u + 0x7FFFu + ((u >> 16) & 1u)) >> 16);
}

// RTN split (hi usable alone; lo compensates).
__device__ __forceinline__ void split1(float v, u16& h, u16& l)
{
    u16 hh = rtn_bf16(v);
    float r = v - bf2f(hh);
    h = hh;
    l = rtn_bf16(r);
}

// Cheap truncation split (3 ops); hi+lo pair accuracy identical.
__device__ __forceinline__ void split1_trunc(float v, u16& h, u16& l)
{
    unsigned bv = __float_as_uint(v);
    unsigned hb = bv & 0xFFFF0000u;
    float r = v - __uint_as_float(hb);
    h = (u16)(hb >> 16);
    l = (u16)(__float_as_uint(r) >> 16);
}

// DPP cross-lane move within 16-lane rows (pure VALU — no DS latency).
template <int CTRL>
__device__ __forceinline__ float dppf(float x)
{
    int r = __builtin_amdgcn_update_dpp(0, __float_as_int(x), CTRL, 0xF, 0xF, true);
    return __int_as_float(r);
}

// ---------------------------------------------------------------------------
// RTN-bf16 converter. ks<0: linear layout. ks>=0: weights are written in
// MFMA-FRAGMENT ORDER — packed[layer][((kt*4+quad)*OUTW + col)*8 + j] =
// W[col][kt*32+quad*8+j] (ks=log2 K, os=log2 OUTW). R5-R9's gen stall was
// root-caused to UNCOALESCED W loads (a wave's 64 lanes at stride K*2 B =
// 64 cache lines per load instruction, ~300+cy service each, 4 serialized
// per k-step = 76-118 us). With fragment-order packing, a wave's B-fragment
// load is 4 contiguous 256 B segments — fully coalesced.
// ---------------------------------------------------------------------------
struct SplitDesc { const float* src; u16* h; int n; int ks; int os; };
struct SplitArgs { SplitDesc d[4]; };

__global__ __launch_bounds__(256) void split_multi(SplitArgs args)
{
    SplitDesc de = args.d[blockIdx.y];
    int idx = (blockIdx.x * 256 + threadIdx.x) * 4;
    if (idx >= de.n) return;
    float4 v = *(const float4*)(de.src + idx);
    ushort4 hv;
    hv.x = rtn_bf16(v.x); hv.y = rtn_bf16(v.y);
    hv.z = rtn_bf16(v.z); hv.w = rtn_bf16(v.w);
    if (de.ks < 0) {
        *(ushort4*)(de.h + idx) = hv;
    } else {
        const int ks = de.ks, os = de.os;
        const int lsz = 1 << (ks + os);
        const int layer = idx >> (ks + os);
        const int fl = idx & (lsz - 1);
        const int col = fl >> ks;
        const int k = fl & ((1 << ks) - 1);
        const int kt = k >> 5, quad = (k >> 3) & 3, j = k & 7;
        const int pidx = layer * lsz + (((((kt << 2) + quad) << os) + col) << 3) + j;
        *(ushort4*)(de.h + pidx) = hv;
    }
}

// ---------------------------------------------------------------------------
// One generator layer (output width 512 -> x LDS update). W in packed
// fragment order: frag(kt,ni) = Wp + quad*4096 + (nb+ni*16)*8 + l16*8
// + kt*16384 (u16 units) — coalesced 4x256B per wave-load. Direct
// global->VGPR (no staging, zero K-loop barriers; x is read-only in-loop).
// 2-step chunks: 4 loads + 8 MFMAs, counted vmcnt overlaps naturally;
// 16 waves (4/SIMD) provide the TLP to hide the remaining latency.
// ---------------------------------------------------------------------------
template <int K, bool RR>
__device__ __forceinline__ void gen_layer(
    u16 (&XhS)[16][520], u16 (&XlS)[16][520],
    const u16* __restrict__ Wp, const float* __restrict__ bias,
    int w, int quad, int l16)
{
    const int nb = w * 32;                    // wave's 32-col chunk (16 waves)
    constexpr int NT = K >> 5;
    f32x4 acc[2] = {};
    float bl2[2];
    bl2[0] = bias[nb + l16];
    bl2[1] = bias[nb + 16 + l16];
    const u16* wb = Wp + (size_t)quad * 4096 + (size_t)nb * 8 + (size_t)l16 * 8;
    #pragma unroll
    for (int kc = 0; kc < NT / 2; ++kc) {
        const int kta = 2 * kc, ktb = 2 * kc + 1;
        bf16x8 b0[2], b1[2];
        b0[0] = *(const bf16x8*)(wb + kta * 16384);
        b0[1] = *(const bf16x8*)(wb + kta * 16384 + 128);
        b1[0] = *(const bf16x8*)(wb + ktb * 16384);
        b1[1] = *(const bf16x8*)(wb + ktb * 16384 + 128);
        bf16x8 a0h = *(const bf16x8*)&XhS[l16][kta * 32 + quad * 8];
        bf16x8 a0l = *(const bf16x8*)&XlS[l16][kta * 32 + quad * 8];
        bf16x8 a1h = *(const bf16x8*)&XhS[l16][ktb * 32 + quad * 8];
        bf16x8 a1l = *(const bf16x8*)&XlS[l16][ktb * 32 + quad * 8];
        acc[0] = MFMA(a0h, b0[0], acc[0]);
        acc[0] = MFMA(a0l, b0[0], acc[0]);
        acc[1] = MFMA(a0h, b0[1], acc[1]);
        acc[1] = MFMA(a0l, b0[1], acc[1]);
        acc[0] = MFMA(a1h, b1[0], acc[0]);
        acc[0] = MFMA(a1l, b1[0], acc[0]);
        acc[1] = MFMA(a1h, b1[1], acc[1]);
        acc[1] = MFMA(a1l, b1[1], acc[1]);
    }
    __syncthreads();                          // all waves done reading x
    #pragma unroll
    for (int ni = 0; ni < 2; ++ni) {
        const int col = nb + ni * 16 + l16;
        #pragma unroll
        for (int r = 0; r < 4; ++r) {
            const int row = quad * 4 + r;
            float v = acc[ni][r] + bl2[ni];
            if (RR) {
                float prev = bf2f(XhS[row][col]) + bf2f(XlS[row][col]);
                v = prev + fmaxf(v, 0.0f);
            }
            u16 hh, ll;
            split1_trunc(v, hh, ll);
            XhS[row][col] = hh;
            XlS[row][col] = ll;
        }
    }
    __syncthreads();                          // x updated for next layer
}

// ---------------------------------------------------------------------------
// FUSED generator: each block owns 16 rows of x, runs ALL 6 layers with x
// resident in LDS (hi/lo bf16, 33 KB). 1024 threads = 16 waves = 4
// waves/SIMD (TLP hides the coalesced W-load latency). W direct
// global->VGPR in fragment-packed order.
// ---------------------------------------------------------------------------
__global__ __launch_bounds__(1024) void gen_fused(
    const float* __restrict__ eps,
    const u16* __restrict__ Win, const u16* __restrict__ Wblk,
    const u16* __restrict__ Wout,
    const float* __restrict__ b_in, const float* __restrict__ b_blk,
    const float* __restrict__ b_out,
    float* __restrict__ xo, u16* __restrict__ xh)
{
    __shared__ u16 XhS[16][520], XlS[16][520];
    const int t = threadIdx.x;
    const int w = t >> 6, lane = t & 63;
    const int quad = lane >> 4, l16 = lane & 15;
    const int bm = blockIdx.x * 16;

    // --- stage eps rows -> x LDS (split1 RTN; 2 elems/thread) ---
    {
        int idx = t * 2;                       // 0..2047 over 16x128
        int row = idx >> 7, col = idx & 127;
        float2 v = *(const float2*)(eps + (size_t)(bm + row) * D + col);
        ushort2 hv, lv;
        split1(v.x, hv.x, lv.x); split1(v.y, hv.y, lv.y);
        *(ushort2*)&XhS[row][col] = hv;
        *(ushort2*)&XlS[row][col] = lv;
    }
    __syncthreads();

    gen_layer<D, false>(XhS, XlS, Win, b_in, w, quad, l16);
    #pragma unroll 1
    for (int i = 0; i < 4; ++i)
        gen_layer<H, true>(XhS, XlS, Wblk + (size_t)i * H * H, b_blk + i * H,
                           w, quad, l16);

    // --- last layer: out width 128 (waves 0-7 only), fp32 xo + RTN xh ---
    if (w < 8) {
        const int n0 = w * 16;
        constexpr int NT = H >> 5;
        f32x4 acc5 = {};
        const float bl = b_out[n0 + l16];
        const u16* wb = Wout + (size_t)quad * 1024 + (size_t)n0 * 8
                             + (size_t)l16 * 8;
        #pragma unroll
        for (int kc = 0; kc < NT / 2; ++kc) {
            const int kta = 2 * kc, ktb = 2 * kc + 1;
            bf16x8 b0 = *(const bf16x8*)(wb + kta * 4096);
            bf16x8 b1 = *(const bf16x8*)(wb + ktb * 4096);
            bf16x8 a0h = *(const bf16x8*)&XhS[l16][kta * 32 + quad * 8];
            bf16x8 a0l = *(const bf16x8*)&XlS[l16][kta * 32 + quad * 8];
            bf16x8 a1h = *(const bf16x8*)&XhS[l16][ktb * 32 + quad * 8];
            bf16x8 a1l = *(const bf16x8*)&XlS[l16][ktb * 32 + quad * 8];
            acc5 = MFMA(a0h, b0, acc5);
            acc5 = MFMA(a0l, b0, acc5);
            acc5 = MFMA(a1h, b1, acc5);
            acc5 = MFMA(a1l, b1, acc5);
        }
        const int col = n0 + l16;
        #pragma unroll
        for (int r = 0; r < 4; ++r) {
            const int gm = bm + quad * 4 + r;
            float v = acc5[r] + bl;
            xo[(size_t)gm * D + col] = v;
            xh[(size_t)gm * D + col] = rtn_bf16(v);
        }
    }
}

// ---------------------------------------------------------------------------
// Deterministic row-norms: nx from xo, ny from y_pos. 4 threads/row, fixed
// order + fixed 2-step shfl tree.
// ---------------------------------------------------------------------------
__global__ __launch_bounds__(256) void rownorm(
    const float* __restrict__ X, const float* __restrict__ Y,
    float* __restrict__ nx, float* __restrict__ ny)
{
    const float* src = blockIdx.y ? Y : X;
    float* dst = blockIdx.y ? ny : nx;
    const int t = threadIdx.x;
    const int row = blockIdx.x * 64 + (t >> 2);
    const int q = t & 3;
    const float* rp = src + (size_t)row * D + q * 32;
    float s = 0.f;
    #pragma unroll
    for (int i = 0; i < 8; ++i) {
        float4 v = *(const float4*)(rp + i * 4);
        s += v.x * v.x + v.y * v.y + v.z * v.z + v.w * v.w;
    }
    s += __shfl_xor(s, 1);
    s += __shfl_xor(s, 2);
    if (q == 0) dst[row] = s;
}

// ---------------------------------------------------------------------------
// Transpose + RTN-bf16 (pure — norms moved to rownorm).
// ---------------------------------------------------------------------------
__global__ __launch_bounds__(256) void transpose_rtn(
    const float* __restrict__ X, const float* __restrict__ Y,
    u16* __restrict__ Xth, u16* __restrict__ Yth)
{
    const float* src = blockIdx.z ? Y : X;
    u16* th = blockIdx.z ? Yth : Xth;
    __shared__ float tile[32][33];
    const int t = threadIdx.x;
    const int r0 = blockIdx.x * 32, c0 = blockIdx.y * 32;
    {
        int rit = t >> 3, coff = (t & 7) * 4;
        float4 v = *(const float4*)(src + (size_t)(r0 + rit) * D + c0 + coff);
        tile[rit][coff + 0] = v.x; tile[rit][coff + 1] = v.y;
        tile[rit][coff + 2] = v.z; tile[rit][coff + 3] = v.w;
    }
    __syncthreads();
    {
        int cit = t >> 3, roff = (t & 7) * 4;
        ushort4 hv;
        hv.x = rtn_bf16(tile[roff + 0][cit]);
        hv.y = rtn_bf16(tile[roff + 1][cit]);
        hv.z = rtn_bf16(tile[roff + 2][cit]);
        hv.w = rtn_bf16(tile[roff + 3][cit]);
        *(ushort4*)(th + (size_t)(c0 + cit) * N + r0 + roff) = hv;
    }
}

// ---------------------------------------------------------------------------
// Distance via SINGLE RTN-bf16 MFMA, fused stats, pos+neg merged. A fp16,
// stored in LOG2 domain. Epilogue in POSITIVE s-domain: raw v_sqrt_f32,
// SC^2 folded into norms, per-element diag cndmask.
// Tile 128(M)x128(N), 4 waves each owning 32 rows x full 128 cols.
// ---------------------------------------------------------------------------
__global__ __launch_bounds__(256) void dist_fused(
    const u16* __restrict__ Xh, const u16* __restrict__ Yh,
    const float* __restrict__ nx, const float* __restrict__ ny,
    f16* __restrict__ Apos, f16* __restrict__ Aneg,
    float* __restrict__ prm_p, float* __restrict__ prs_p,
    float* __restrict__ pcm_p, float* __restrict__ pcs_p,
    float* __restrict__ prm_n, float* __restrict__ prs_n)
{
    const int mat = blockIdx.z;                // 0: X vs Y ; 1: X vs X
    const u16* Bhp = mat ? Xh : Yh;
    const float* nb = mat ? nx : ny;
    f16* Out = mat ? Aneg : Apos;
    float* prm = mat ? prm_n : prm_p;
    float* prs = mat ? prs_n : prs_p;

    __shared__ u16 XhS[128][40], YhS[128][40];
    const int t = threadIdx.x;
    const int w = t >> 6, lane = t & 63;
    const int quad = lane >> 4, l16 = lane & 15;
    const int bm = blockIdx.y * 128, bn = blockIdx.x * 128;
    f32x4 acc[2][8] = {};

    for (int k0 = 0; k0 < D; k0 += 32) {
        __syncthreads();
        #pragma unroll
        for (int p = 0; p < 2; ++p) {
            int slot = t + p * 256;            // 512 slots = 128 rows x 4 octets
            int row = slot >> 2, koff = (slot & 3) << 3;
            *(u16x8*)&XhS[row][koff] =
                *(const u16x8*)(Xh + (size_t)(bm + row) * D + k0 + koff);
        }
        #pragma unroll
        for (int p = 0; p < 2; ++p) {
            int slot = t + p * 256;
            int row = slot >> 2, koff = (slot & 3) << 3;
            int pr = ((row & 3) << 4) | ((row & 63) >> 2) | (row & 64);
            int kf = koff ^ (((pr >> 4) & 3) << 3);
            *(u16x8*)&YhS[pr][kf] =
                *(const u16x8*)(Bhp + (size_t)(bn + row) * D + k0 + koff);
        }
        __syncthreads();
        bf16x8 af[2], bhf[8];
        #pragma unroll
        for (int mi = 0; mi < 2; ++mi)
            af[mi] = *(const bf16x8*)&XhS[w * 32 + mi * 16 + l16][quad * 8];
        #pragma unroll
        for (int ni = 0; ni < 8; ++ni) {
            int nn = ni & 3, hf = ni >> 2;
            bhf[ni] = *(const bf16x8*)
                &YhS[hf * 64 + nn * 16 + l16][(quad * 8) ^ (nn << 3)];
        }
        #pragma unroll
        for (int mi = 0; mi < 2; ++mi)
            #pragma unroll
            for (int ni = 0; ni < 8; ++ni)
                acc[mi][ni] = MFMA(af[mi], bhf[ni], acc[mi][ni]);
    }
    // lane's 8 j's: jb..jb+3 and jb+64..jb+67
    const int jb = bn + (l16 << 2);
    const float SC2 = SC_LOG2 * SC_LOG2;
    const float c2 = -2.0f * SC2;
    const float4 n0v = *(const float4*)(nb + jb);
    const float4 n1v = *(const float4*)(nb + jb + 64);
    const float nl[8] = {n0v.x * SC2, n0v.y * SC2, n0v.z * SC2, n0v.w * SC2,
                         n1v.x * SC2, n1v.y * SC2, n1v.z * SC2, n1v.w * SC2};
    // --- transform in place to s = dist*SC (positive domain) + f16 stores ---
    #pragma unroll
    for (int mi = 0; mi < 2; ++mi)
        #pragma unroll
        for (int r = 0; r < 4; ++r) {
            const int gm = bm + w * 32 + mi * 16 + quad * 4 + r;
            const float nxm = nx[gm] * SC2;
            f16x4 ov0, ov1;
            #pragma unroll
            for (int nn = 0; nn < 4; ++nn) {
                float s0 = fsqrt(fmaxf(
                    fmaf(acc[mi][nn][r], c2, nxm + nl[nn]), 0.f));
                float s1 = fsqrt(fmaxf(
                    fmaf(acc[mi][4 + nn][r], c2, nxm + nl[4 + nn]), 0.f));
                if (mat) {
                    if (gm == jb + nn) s0 = 5.0e6f;
                    if (gm == jb + 64 + nn) s1 = 5.0e6f;
                }
                acc[mi][nn][r] = s0;
                acc[mi][4 + nn][r] = s1;
                ov0[nn] = (f16)(-s0);
                ov1[nn] = (f16)(-s1);
            }
            *(f16x4*)(Out + (size_t)gm * N + jb) = ov0;
            *(f16x4*)(Out + (size_t)gm * N + jb + 64) = ov1;
        }
    // --- row mins of s (== -row max of a): in-lane over 8 ni, DPP over l16 ---
    float m[2][4];
    #pragma unroll
    for (int mi = 0; mi < 2; ++mi)
        #pragma unroll
        for (int r = 0; r < 4; ++r) {
            float v = fminf(fminf(fminf(acc[mi][0][r], acc[mi][1][r]),
                                  fminf(acc[mi][2][r], acc[mi][3][r])),
                            fminf(fminf(acc[mi][4][r], acc[mi][5][r]),
                                  fminf(acc[mi][6][r], acc[mi][7][r])));
            v = fminf(v, dppf<0xB1>(v));
            v = fminf(v, dppf<0x4E>(v));
            v = fminf(v, dppf<0x141>(v));
            v = fminf(v, dppf<0x140>(v));
            m[mi][r] = v;
        }
    // --- wave-shared shift mn (min s over the wave's 32 rows x 128 cols) ---
    float mn = fminf(fminf(fminf(m[0][0], m[0][1]), fminf(m[0][2], m[0][3])),
                     fminf(fminf(m[1][0], m[1][1]), fminf(m[1][2], m[1][3])));
    mn = fminf(mn, __shfl_xor(mn, 16));
    mn = fminf(mn, __shfl_xor(mn, 32));
    // --- single exp pass: e = 2^(mn - s) feeds row sums (sig) + col sums ---
    float sig[2][4] = {};
    float cs[8] = {};
    #pragma unroll
    for (int mi = 0; mi < 2; ++mi)
        #pragma unroll
        for (int ni = 0; ni < 8; ++ni) {
            float e0 = fexp2(mn - acc[mi][ni][0]);
            float e1 = fexp2(mn - acc[mi][ni][1]);
            float e2 = fexp2(mn - acc[mi][ni][2]);
            float e3 = fexp2(mn - acc[mi][ni][3]);
            sig[mi][0] += e0; sig[mi][1] += e1;
            sig[mi][2] += e2; sig[mi][3] += e3;
            cs[ni] += (e0 + e1) + (e2 + e3);
        }
    // --- row partials: DPP tree-sum sig, rescale to row max (a-domain) ---
    const int ct = blockIdx.x;
    #pragma unroll
    for (int mi = 0; mi < 2; ++mi)
        #pragma unroll
        for (int r = 0; r < 4; ++r) {
            float s = sig[mi][r];
            s += dppf<0xB1>(s);
            s += dppf<0x4E>(s);
            s += dppf<0x141>(s);
            s += dppf<0x140>(s);
            s *= fexp2(m[mi][r] - mn);
            if (l16 == 0) {
                int grow = bm + w * 32 + mi * 16 + quad * 4 + r;
                prm[(size_t)ct * N + grow] = -m[mi][r];
                prs[(size_t)ct * N + grow] = s;
            }
        }
    // --- col partials (pos only): quad-reduce cs, shift is -mn (uniform) ---
    if (mat == 0) {
        const int rt = blockIdx.y * 4 + w;      // 32-row tiles -> 128 planes
        #pragma unroll
        for (int ni = 0; ni < 8; ++ni) {
            cs[ni] += __shfl_xor(cs[ni], 16);
            cs[ni] += __shfl_xor(cs[ni], 32);
        }
        if (quad == 0) {
            float4 c0 = {cs[0], cs[1], cs[2], cs[3]};
            float4 c1 = {cs[4], cs[5], cs[6], cs[7]};
            float4 m4 = {-mn, -mn, -mn, -mn};
            *(float4*)(pcs_p + (size_t)rt * N + jb) = c0;
            *(float4*)(pcs_p + (size_t)rt * N + jb + 64) = c1;
            *(float4*)(pcm_p + (size_t)rt * N + jb) = m4;
            *(float4*)(pcm_p + (size_t)rt * N + jb + 64) = m4;
        }
    }
}

// ---------------------------------------------------------------------------
// Combine partials into row/col softmax stats — parallel (192 x 256).
// ---------------------------------------------------------------------------
__global__ __launch_bounds__(256) void stats_combine(
    const float* __restrict__ prm_p, const float* __restrict__ prs_p,
    const float* __restrict__ prm_n, const float* __restrict__ prs_n,
    const float* __restrict__ pcm_p, const float* __restrict__ pcs_p,
    float* __restrict__ m_row, float* __restrict__ isr,
    float* __restrict__ m_col, float* __restrict__ isc)
{
    __shared__ float Ms[4][64], Ss[4][64];
    const int t = threadIdx.x;
    const int g = t >> 6, l = t & 63;
    const int idx = blockIdx.x * 64 + l;

    float m = -3.0e38f, s = 0.f;
    if (idx < N) {
        const int i = idx;
        const int c0 = g * 8;
        #pragma unroll 4
        for (int c = c0; c < c0 + 8; ++c) {
            m = fmaxf(m, prm_p[(size_t)c * N + i]);
            m = fmaxf(m, prm_n[(size_t)c * N + i]);
        }
        #pragma unroll 4
        for (int c = c0; c < c0 + 8; ++c) {
            s += prs_p[(size_t)c * N + i] * fexp2(prm_p[(size_t)c * N + i] - m);
            s += prs_n[(size_t)c * N + i] * fexp2(prm_n[(size_t)c * N + i] - m);
        }
    } else {
        const int mat = (idx - N) >> 12;
        const int j = idx & (N - 1);
        const float* pm = mat ? prm_n : pcm_p;
        const float* ps = mat ? prs_n : pcs_p;
        const int cnt = mat ? 8 : 32;
        const int cb = g * cnt;
        #pragma unroll 4
        for (int c = cb; c < cb + cnt; ++c)
            m = fmaxf(m, pm[(size_t)c * N + j]);
        #pragma unroll 4
        for (int c = cb; c < cb + cnt; ++c)
            s += ps[(size_t)c * N + j] * fexp2(pm[(size_t)c * N + j] - m);
    }
    Ms[g][l] = m; Ss[g][l] = s;
    __syncthreads();
    if (g == 0) {
        float m0 = Ms[0][l], m1 = Ms[1][l], m2 = Ms[2][l], m3 = Ms[3][l];
        float mm = fmaxf(fmaxf(m0, m1), fmaxf(m2, m3));
        float ss = Ss[0][l] * fexp2(m0 - mm) + Ss[1][l] * fexp2(m1 - mm)
                 + Ss[2][l] * fexp2(m2 - mm) + Ss[3][l] * fexp2(m3 - mm);
        if (idx < N) {
            m_row[idx] = mm;
            isr[idx] = 1.0f / sqrtf(ss);
        } else {
            const int mat = (idx - N) >> 12;
            const int j = idx & (N - 1);
            m_col[mat * N + j] = mm;
            isc[mat * N + j] = 1.0f / sqrtf(ss);
        }
    }
}

// ---------------------------------------------------------------------------
// pv via MFMA: A fp16 tile (log2 domain) -> P (fp32 rowsums -> per-KSPLIT
// partial stores, deterministic), split P (trunc) to bf16 hi/lo in LDS,
// MFMA P @ B (B = RTN-bf16 transposed [d][j], hi only).
// ---------------------------------------------------------------------------
__global__ __launch_bounds__(256) void pv_mfma(
    const f16* __restrict__ Apos, const f16* __restrict__ Aneg,
    const u16* __restrict__ Yth, const u16* __restrict__ Xth,
    const float* __restrict__ m_row, const float* __restrict__ isr,
    const float* __restrict__ m_col, const float* __restrict__ isc,
    float* __restrict__ u_part, float* __restrict__ w_part,
    float* __restrict__ sp_part, float* __restrict__ sn_part)
{
    const int mat = blockIdx.z;
    const f16* Am = mat ? Aneg : Apos;
    const u16* Bh = mat ? Xth : Yth;
    const float* mc = m_col + mat * N;
    const float* ic = isc + mat * N;
    float* Cp = (mat ? w_part : u_part) + (size_t)blockIdx.y * (N * D);
    float* spn = (mat ? sn_part : sp_part) + (size_t)blockIdx.y * N;

    __shared__ u16 BhS[128][72];
    __shared__ u16 PhS[64][72], PlS[64][72];
    __shared__ float mrS[64], isrS[64];

    const int t = threadIdx.x;
    const int w = t >> 6, lane = t & 63;
    const int quad = lane >> 4, l16 = lane & 15;
    const int bm = blockIdx.x * 64;
    const int jbase = blockIdx.y * (N / KSPLIT);
    const int arow = t >> 4;          // 0..15
    const int aj = (t & 15) << 2;     // 0..60

    if (t < 64) { mrS[t] = m_row[bm + t]; isrS[t] = isr[bm + t]; }

    f32x4 acc[8] = {};
    float rs[4] = {0.f, 0.f, 0.f, 0.f};

    for (int jt = 0; jt < (N / KSPLIT) / 64; ++jt) {
        const int j0 = jbase + jt * 64;
        __syncthreads();   // protect previous iteration's LDS reads (+ mrS init)
        #pragma unroll
        for (int p = 0; p < 4; ++p) {
            int slot = t + p * 256;
            int d = slot >> 3, joff = (slot & 7) << 3;
            *(u16x8*)&BhS[d][joff] = *(const u16x8*)(Bh + (size_t)d * N + j0 + joff);
        }
        float4 mcv = *(const float4*)(mc + j0 + aj);
        float4 icv = *(const float4*)(ic + j0 + aj);
        #pragma unroll
        for (int s = 0; s < 4; ++s) {
            int row = arow + s * 16;
            f16x4 av = *(const f16x4*)(Am + (size_t)(bm + row) * N + j0 + aj);
            float mr = mrS[row], sr = isrS[row];
            float p0 = fexp2((float)av.x - 0.5f * (mr + mcv.x)) * (sr * icv.x);
            float p1 = fexp2((float)av.y - 0.5f * (mr + mcv.y)) * (sr * icv.y);
            float p2 = fexp2((float)av.z - 0.5f * (mr + mcv.z)) * (sr * icv.z);
            float p3 = fexp2((float)av.w - 0.5f * (mr + mcv.w)) * (sr * icv.w);
            rs[s] += p0 + p1 + p2 + p3;
            ushort4 hv, lv;
            split1_trunc(p0, hv.x, lv.x); split1_trunc(p1, hv.y, lv.y);
            split1_trunc(p2, hv.z, lv.z); split1_trunc(p3, hv.w, lv.w);
            *(ushort4*)&PhS[row][aj] = hv;
            *(ushort4*)&PlS[row][aj] = lv;
        }
        __syncthreads();
        #pragma unroll
        for (int ks = 0; ks < 2; ++ks) {
            const int kk = ks * 32 + quad * 8;
            bf16x8 ph = *(const bf16x8*)&PhS[w * 16 + l16][kk];
            bf16x8 pl = *(const bf16x8*)&PlS[w * 16 + l16][kk];
            #pragma unroll
            for (int ni = 0; ni < 8; ++ni) {
                bf16x8 bh = *(const bf16x8*)&BhS[ni * 16 + l16][kk];
                acc[ni] = MFMA(ph, bh, acc[ni]);
                acc[ni] = MFMA(pl, bh, acc[ni]);
            }
        }
    }
    #pragma unroll
    for (int ni = 0; ni < 8; ++ni)
        #pragma unroll
        for (int r = 0; r < 4; ++r) {
            int row = w * 16 + quad * 4 + r;
            int col = ni * 16 + l16;
            Cp[(size_t)(bm + row) * D + col] = acc[ni][r];
        }
    #pragma unroll
    for (int s = 0; s < 4; ++s) {
        float v = rs[s];
        v += __shfl_xor(v, 1); v += __shfl_xor(v, 2);
        v += __shfl_xor(v, 4); v += __shfl_xor(v, 8);
        if (l16 == 0) spn[bm + arow + s * 16] = v;   // unique writer per (y,row)
    }
}

// ---------------------------------------------------------------------------
// Sum split-K partials (fixed order), V = sn*u - sp*sn*w, per-block V^2
// partial into acc_part (no atomics — finalize does the deterministic sum).
// ---------------------------------------------------------------------------
__global__ __launch_bounds__(256) void final_reduce(const float* __restrict__ u_part,
    const float* __restrict__ w_part, const float* __restrict__ sp_part,
    const float* __restrict__ sn_part, double* __restrict__ acc_part)
{
    __shared__ float red[256];
    const int t = threadIdx.x;
    const int idx = blockIdx.x * 256 + t;
    float u = 0.f, w = 0.f;
    #pragma unroll
    for (int c = 0; c < KSPLIT; ++c) {
        u += u_part[(size_t)c * (N * D) + idx];
        w += w_part[(size_t)c * (N * D) + idx];
    }
    const int i = idx >> 7;
    float sp = 0.f, sn = 0.f;
    #pragma unroll
    for (int c = 0; c < KSPLIT; ++c) {
        sp += sp_part[(size_t)c * N + i];
        sn += sn_part[(size_t)c * N + i];
    }
    const float v = sn * u - sp * sn * w;
    red[t] = v * v; __syncthreads();
    for (int s = 128; s > 0; s >>= 1) { if (t < s) red[t] += red[t + s]; __syncthreads(); }
    if (!t) acc_part[blockIdx.x] = (double)red[0];
}

// ---------------------------------------------------------------------------
// Deterministic final sum: 2048 double partials, fixed-order + fixed tree.
// ---------------------------------------------------------------------------
__global__ __launch_bounds__(256) void finalize(const double* __restrict__ acc_part,
                                                float* __restrict__ out)
{
    __shared__ double red[256];
    const int t = threadIdx.x;
    double s = 0.0;
    #pragma unroll
    for (int i = 0; i < 8; ++i) s += acc_part[t + i * 256];
    red[t] = s; __syncthreads();
    for (int st = 128; st > 0; st >>= 1) {
        if (t < st) red[t] += red[t + st];
        __syncthreads();
    }
    if (!t) out[0] = (float)(red[0] * (1.0 / ((double)N * (double)D)));
}

// ---------------------------------------------------------------------------
extern "C" void kernel_launch(void* const* d_in, const int* in_sizes, int n_in,
                              void* d_out, int out_size, void* d_ws, size_t ws_size,
                              hipStream_t stream)
{
    const float* y_pos = (const float*)d_in[0];
    const float* eps   = (const float*)d_in[1];
    const float* W_in  = (const float*)d_in[2];
    const float* b_in  = (const float*)d_in[3];
    const float* W_blk = (const float*)d_in[4];
    const float* b_blk = (const float*)d_in[5];
    const float* W_out = (const float*)d_in[6];
    const float* b_out = (const float*)d_in[7];
    float* out = (float*)d_out;
    (void)in_sizes; (void)n_in; (void)out_size; (void)ws_size;

    char* p = (char*)d_ws;
    auto alloc = [&](size_t bytes) {
        char* r = p;
        p += (bytes + 255) & ~(size_t)255;
        return r;
    };
    // --- small arrays ---
    double* acc_part = (double*)alloc(2048 * 8);
    float* sp_part = (float*)alloc((size_t)KSPLIT * N * 4);
    float* sn_part = (float*)alloc((size_t)KSPLIT * N * 4);
    float* m_row  = (float*)alloc(N * 4);
    float* isr    = (float*)alloc(N * 4);
    float* m_col  = (float*)alloc(2 * N * 4);
    float* isc    = (float*)alloc(2 * N * 4);
    float* nx     = (float*)alloc(N * 4);
    float* ny     = (float*)alloc(N * 4);
    // --- xo fp32 + bf16 x/y arrays (hi only) ---
    float* xo  = (float*)alloc((size_t)N * D * 4);
    u16* xh    = (u16*)alloc((size_t)N * D * 2);
    u16* xth   = (u16*)alloc((size_t)N * D * 2);
    u16* yh    = (u16*)alloc((size_t)N * D * 2);
    u16* yth   = (u16*)alloc((size_t)N * D * 2);
    // --- shared region (16 MB): weights hi (2.3 MB, dead after gen_fused),
    //     then stats partials (6 MB), then u/w_part (16 MB) ---
    char* genreg = alloc((size_t)KSPLIT * N * D * 4 * 2);
    u16* wih = (u16*)genreg;
    u16* wbh = wih + (size_t)H * D;
    u16* woh = wbh + (size_t)4 * H * H;
    // aliases (disjoint lifetimes, stream-ordered):
    float* prm_p = (float*)genreg;                 // 32*N each = 0.5 MB
    float* prs_p = prm_p + 32 * N;
    float* prm_n = prs_p + 32 * N;
    float* prs_n = prm_n + 32 * N;
    float* pcm_p = prs_n + 32 * N;                 // 128*N = 2 MB each
    float* pcs_p = pcm_p + 128 * N;                // ends at 6 MB
    float* u_part = (float*)genreg;                // KSPLIT*N*D = 8 MB
    float* w_part = u_part + (size_t)KSPLIT * N * D;
    // --- the big ones (64 MB, fp16) ---
    f16* Apos = (f16*)alloc((size_t)N * N * 2);
    f16* Aneg = (f16*)alloc((size_t)N * N * 2);

    // --- RTN-convert y_pos (linear) + weights (MFMA-fragment packed) ---
    SplitArgs sa;
    sa.d[0] = { y_pos, yh,  N * D,     -1, 0 };
    sa.d[1] = { W_in,  wih, H * D,      7, 9 };   // K=128, OUTW=512
    sa.d[2] = { W_blk, wbh, 4 * H * H,  9, 9 };   // K=512, OUTW=512, 4 layers
    sa.d[3] = { W_out, woh, D * H,      9, 7 };   // K=512, OUTW=128
    split_multi<<<dim3(1024, 4), 256, 0, stream>>>(sa);

    // --- FUSED generator: whole 6-layer chain, x LDS-resident ---
    gen_fused<<<N / 16, 1024, 0, stream>>>(eps, wih, wbh, woh,
                                           b_in, b_blk, b_out, xo, xh);

    // --- deterministic row norms (nx from xo, ny from y_pos) ---
    rownorm<<<dim3(N / 64, 2), 256, 0, stream>>>(xo, y_pos, nx, ny);

    // --- RTN transposes ---
    transpose_rtn<<<dim3(N / 32, D / 32, 2), 256, 0, stream>>>(
        xo, y_pos, xth, yth);

    // --- distance matrices (fp16 log2-domain, single-bf16 MFMA) + stats ---
    dist_fused<<<dim3(N / 128, N / 128, 2), 256, 0, stream>>>(
        xh, yh, nx, ny, Apos, Aneg,
        prm_p, prs_p, pcm_p, pcs_p, prm_n, prs_n);

    // --- combine partials into m_row/isr, m_col/isc (parallel) ---
    stats_combine<<<192, 256, 0, stream>>>(prm_p, prs_p, prm_n, prs_n,
                                           pcm_p, pcs_p,
                                           m_row, isr, m_col, isc);

    // --- P@V via MFMA (P built on the fly; sp/sn deterministic partials) ---
    pv_mfma<<<dim3(N / 64, KSPLIT, 2), 256, 0, stream>>>(Apos, Aneg,
        yth, xth, m_row, isr, m_col, isc, u_part, w_part, sp_part, sn_part);

    // --- combine partials, V^2 reduction (no atomics) ---
    final_reduce<<<(N * D) / 256, 256, 0, stream>>>(u_part, w_part,
                                                    sp_part, sn_part, acc_part);
    finalize<<<1, 256, 0, stream>>>(acc_part, out);
}